// Round 1
// 444.111 us; speedup vs baseline: 1.0369x; 1.0369x over previous
//
#include <hip/hip_runtime.h>
#include <math.h>

// Problem constants
#define B 32
#define N 4096
#define D 128
#define KTOP 512
#define NPB 2048
#define MSEG (B * NPB)      // 65536
#define E (B * N)           // 131072
#define MAXC 32             // max edges per segment (Binomial(4096,1/2048), mean 2)
#define K7ROWS 16           // rows per k7 block

// ---------------------------------------------------------------------------
// K0: per-batch precompute (fp64): query = cat(qh,qr,qt)@W_q+b_q,
// u_d = q_d*W1_d - W2_d + W3_d, v = W_a @ u, c2 = q.(W2+W3)+b_att+b_a.u
// 384 threads: 3 groups of 128 each handle one input segment (chain 3x shorter
// than the old 128-thread version), then one W_a row per thread in phase B.
// ---------------------------------------------------------------------------
__global__ __launch_bounds__(384) void k0_precompute(
    const float* __restrict__ qh, const float* __restrict__ qr,
    const float* __restrict__ qt, const float* __restrict__ Wq,
    const float* __restrict__ bq, const float* __restrict__ Wa,
    const float* __restrict__ ba, const float* __restrict__ Watt,
    const float* __restrict__ batt, float* __restrict__ vf,
    float* __restrict__ c2f) {
  int b = blockIdx.x;
  int tid = threadIdx.x;
  int d = tid & 127;
  int g = tid >> 7;  // 0..2, wave-uniform (384 = 6 waves)
  __shared__ double part[3][128];
  __shared__ double u[128];
  __shared__ double red[128];
  const float* xs = (g == 0 ? qh : (g == 1 ? qr : qt)) + b * 128;
  const float* Wg = Wq + g * 128 * 128;
  double a0 = 0, a1 = 0, a2 = 0, a3 = 0;
#pragma unroll 4
  for (int i = 0; i < 128; i += 4) {
    a0 += (double)xs[i] * (double)Wg[i * 128 + d];
    a1 += (double)xs[i + 1] * (double)Wg[(i + 1) * 128 + d];
    a2 += (double)xs[i + 2] * (double)Wg[(i + 2) * 128 + d];
    a3 += (double)xs[i + 3] * (double)Wg[(i + 3) * 128 + d];
  }
  part[g][d] = (a0 + a1) + (a2 + a3);
  __syncthreads();
  if (g == 0) {
    double acc = (double)bq[d] + part[0][d] + part[1][d] + part[2][d];
    double w1 = (double)Watt[d], w2 = (double)Watt[128 + d],
           w3 = (double)Watt[256 + d];
    double ud = acc * w1 - w2 + w3;
    u[d] = ud;
    red[d] = acc * (w2 + w3) + (double)ba[d] * ud;
  }
  __syncthreads();
  for (int s = 64; s > 0; s >>= 1) {
    if (tid < s) red[tid] += red[tid + s];
    __syncthreads();
  }
  if (tid == 0) c2f[b] = (float)(red[0] + (double)batt[0]);
  // phase B: one W_a row per thread (384 rows, 384 threads)
  {
    double v0 = 0, v1 = 0, v2 = 0, v3 = 0;
    const float* Wr = Wa + tid * 128;
#pragma unroll 4
    for (int dd = 0; dd < 128; dd += 4) {
      v0 += (double)Wr[dd] * u[dd];
      v1 += (double)Wr[dd + 1] * u[dd + 1];
      v2 += (double)Wr[dd + 2] * u[dd + 2];
      v3 += (double)Wr[dd + 3] * u[dd + 3];
    }
    vf[b * 384 + tid] = (float)((v0 + v1) + (v2 + v3));
  }
}

// ---------------------------------------------------------------------------
// K1: per-edge attention, fp32. 32 lanes per edge, float4 per lane.
// Software-pipelined depth 4 (16 float4 payloads in registers per lane) so
// each wave keeps ~16 loads outstanding. Segment ids (tidx) are loaded in the
// prologue BEFORE any payload prefetch so the per-iteration atomic-address
// wait never drains the pipeline (vmcnt is in-order).
// agg accumulated as fp64 atomics (order-independent to ~1e-15, far below the
// rank-512 boundary gap ~1e-3 -> ranking stable).
// ---------------------------------------------------------------------------
__global__ __launch_bounds__(256) void k1_att(
    const float* __restrict__ r, const float* __restrict__ t,
    const float* __restrict__ tm, const float* __restrict__ hidden,
    const float* __restrict__ Wrule, const float* __restrict__ brule,
    const float* __restrict__ vf, const float* __restrict__ c2f,
    const int* __restrict__ tidx, float* __restrict__ attw,
    double* __restrict__ aggd) {
  int tid = threadIdx.x;
  int h = tid >> 5;       // half-wave id 0..7
  int l = tid & 31;       // lane within 32
  int base = blockIdx.x * 64;
  int b = base >> 12;     // batch (uniform over block)
  const float4* vb = (const float4*)(vf + b * 384);
  float4 v0 = vb[l];
  float4 v1 = vb[32 + l];
  float4 v2 = vb[64 + l];
  float4 wr = ((const float4*)Wrule)[l];
  float c2 = c2f[b];
  float br = brule[0];
  // ---- prologue 1: segment ids, issued first ----
  int mseg[8];
#pragma unroll
  for (int i = 0; i < 8; ++i) mseg[i] = tidx[base + i * 8 + h];
  // ---- prologue 2: payloads for edges 0..3 ----
  float4 ra[4], ta[4], ma[4], ha[4];
  size_t lo = (size_t)(l * 4);
#pragma unroll
  for (int i = 0; i < 4; ++i) {
    size_t eo = (size_t)(base + i * 8 + h) * 128 + lo;
    ra[i] = *(const float4*)(r + eo);
    ta[i] = *(const float4*)(t + eo);
    ma[i] = *(const float4*)(tm + eo);
    ha[i] = *(const float4*)(hidden + eo);
  }
#pragma unroll
  for (int i = 0; i < 8; ++i) {
    float4 A = ra[i & 3], T = ta[i & 3], M = ma[i & 3], H = ha[i & 3];
    if (i < 4) {  // prefetch edge i+4 into the slot we just consumed
      size_t eo = (size_t)(base + (i + 4) * 8 + h) * 128 + lo;
      ra[i & 3] = *(const float4*)(r + eo);
      ta[i & 3] = *(const float4*)(t + eo);
      ma[i & 3] = *(const float4*)(tm + eo);
      ha[i & 3] = *(const float4*)(hidden + eo);
    }
    float p1 = A.x * v0.x + A.y * v0.y + A.z * v0.z + A.w * v0.w;
    p1 += T.x * v1.x + T.y * v1.y + T.z * v1.z + T.w * v1.w;
    p1 += M.x * v2.x + M.y * v2.y + M.z * v2.z + M.w * v2.w;
    float p2 = H.x * wr.x + H.y * wr.y + H.z * wr.z + H.w * wr.w;
#pragma unroll
    for (int off = 16; off > 0; off >>= 1) {
      p1 += __shfl_xor(p1, off);
      p2 += __shfl_xor(p2, off);
    }
    if (l == 0) {
      int e = base + i * 8 + h;
      float a1 = 1.0f / (1.0f + expf(-(p1 + c2)));
      float a2 = 1.0f / (1.0f + expf(-(p2 + br)));
      float a = 0.5f * (a1 + a2);
      attw[e] = a;
      atomicAdd(&aggd[mseg[i]], (double)a);
    }
  }
}

// ---------------------------------------------------------------------------
// KB: build fixed-stride per-segment edge lists via atomics.
// ---------------------------------------------------------------------------
__global__ __launch_bounds__(256) void kb_build(const int* __restrict__ tidx,
                                                int* __restrict__ counts,
                                                int* __restrict__ lists) {
  int e = blockIdx.x * 256 + threadIdx.x;
  int m = tidx[e];
  int pos = atomicAdd(&counts[m], 1);
  if (pos < MAXC) lists[m * MAXC + pos] = e;
}

// ---------------------------------------------------------------------------
// K6: exact top-K by rank counting on fp64 agg. Block = (batch, 256 elems).
// rank(i) = #{j : v_j > v_i || (v_j == v_i && j < i)}  == lax.top_k position.
// ---------------------------------------------------------------------------
__global__ __launch_bounds__(256) void k6_topk(
    const double* __restrict__ aggd, const int* __restrict__ tail_nodes,
    float* __restrict__ out_nodes, int* __restrict__ idxw) {
  __shared__ double sv[2048];
  int b = blockIdx.x >> 3;
  int chunk = blockIdx.x & 7;
  int tid = threadIdx.x;
  for (int s = tid; s < 2048; s += 256) sv[s] = aggd[b * 2048 + s];
  __syncthreads();
  int i = chunk * 256 + tid;
  double vi = sv[i];
  int rank = 0;
#pragma unroll 8
  for (int j = 0; j < 2048; ++j) {
    double vj = sv[j];
    rank += (vj > vi) || (vj == vi && j < i);
  }
  if (rank < KTOP) {
    int gm = b * 2048 + i;
    int p = b * KTOP + rank;
    out_nodes[p * 2 + 0] = (float)tail_nodes[gm * 3 + 1];
    out_nodes[p * 2 + 1] = (float)tail_nodes[gm * 3 + 2];
    idxw[p] = gm;
  }
}

// ---------------------------------------------------------------------------
// K7: selected rows only. Phase 1: gather edges, segment-sum message/hidden
// into LDS es[16][128] (+out_hid). Phase 2: out_emd = es @ W_out + b_out with
// W_out from L2 (64 KB, broadcast reads) and 8 independent accs/thread.
// Grid 1024 x 256, LDS 8 KB -> high occupancy, no long dependent chains.
// ---------------------------------------------------------------------------
__global__ __launch_bounds__(256) void k7_out(
    const float* __restrict__ tail_emd, const float* __restrict__ r,
    const float* __restrict__ tm, const float* __restrict__ hidden,
    const float* __restrict__ qh, const float* __restrict__ attw,
    const int* __restrict__ counts, const int* __restrict__ lists,
    const float* __restrict__ Wout, const float* __restrict__ bout,
    const int* __restrict__ idxw, float* __restrict__ out_emd,
    float* __restrict__ out_hid) {
  __shared__ float es[K7ROWS][128];
  int tid = threadIdx.x;
  int sub = tid >> 7, d = tid & 127;
  int base = blockIdx.x * K7ROWS;
  // ---- phase 1: gather + segment sums ----
  for (int j = 0; j < K7ROWS; j += 2) {
    int row = base + j + sub;
    int m = idxw[row];
    int b = m >> 11;
    int cnt = counts[m];
    if (cnt > MAXC) cnt = MAXC;
    float accT = tail_emd[(size_t)m * 128 + d];
    float accH = 0.f;
    float qhd = qh[b * 128 + d];
    for (int jj = 0; jj < cnt; ++jj) {
      int e = lists[m * MAXC + jj];
      float a = attw[e];
      size_t eo = (size_t)e * 128 + d;
      accT += a * (qhd + r[eo] + tm[eo]);
      accH += hidden[eo];
    }
    es[j + sub][d] = accT;
    out_hid[(size_t)row * 128 + d] = accH;
  }
  __syncthreads();
  // ---- phase 2: GEMM es(16x128) @ Wout(128x128) ----
  int cg = tid & 31;   // columns cg*4 .. cg*4+3
  int rg = tid >> 5;   // row pair rg*2, rg*2+1
  float4 bo = *(const float4*)(bout + cg * 4);
  float acc0x = bo.x, acc0y = bo.y, acc0z = bo.z, acc0w = bo.w;
  float acc1x = bo.x, acc1y = bo.y, acc1z = bo.z, acc1w = bo.w;
#pragma unroll 4
  for (int i = 0; i < 128; ++i) {
    float4 w = *(const float4*)(Wout + i * 128 + cg * 4);
    float e0 = es[rg * 2 + 0][i];
    float e1 = es[rg * 2 + 1][i];
    acc0x += e0 * w.x; acc0y += e0 * w.y; acc0z += e0 * w.z; acc0w += e0 * w.w;
    acc1x += e1 * w.x; acc1y += e1 * w.y; acc1z += e1 * w.z; acc1w += e1 * w.w;
  }
  size_t r0 = (size_t)(base + rg * 2) * 128 + cg * 4;
  *(float4*)(out_emd + r0) = make_float4(acc0x, acc0y, acc0z, acc0w);
  *(float4*)(out_emd + r0 + 128) = make_float4(acc1x, acc1y, acc1z, acc1w);
}

// ---------------------------------------------------------------------------
extern "C" void kernel_launch(void* const* d_in, const int* in_sizes, int n_in,
                              void* d_out, int out_size, void* d_ws,
                              size_t ws_size, hipStream_t stream) {
  const float* q_head = (const float*)d_in[0];
  const float* q_rel = (const float*)d_in[1];
  const float* q_time = (const float*)d_in[2];
  const float* r_nb = (const float*)d_in[3];
  const float* t_nb = (const float*)d_in[4];
  const float* tm_nb = (const float*)d_in[5];
  const float* hidden = (const float*)d_in[6];
  const float* tail_emd = (const float*)d_in[7];
  const int* tail_index = (const int*)d_in[8];
  const int* tail_nodes = (const int*)d_in[9];
  const float* W_q = (const float*)d_in[10];
  const float* b_q = (const float*)d_in[11];
  const float* W_a = (const float*)d_in[12];
  const float* b_a = (const float*)d_in[13];
  const float* W_att = (const float*)d_in[14];
  const float* b_att = (const float*)d_in[15];
  const float* W_rule = (const float*)d_in[16];
  const float* b_rule = (const float*)d_in[17];
  const float* W_out = (const float*)d_in[18];
  const float* b_out = (const float*)d_in[19];

  // Workspace layout: counts and aggd contiguous -> single memset.
  char* ws = (char*)d_ws;
  float* vf = (float*)(ws + 0);              // 32*384*4 = 49152
  float* c2f = (float*)(ws + 49152);         // 128 -> pad to 49280
  float* attw = (float*)(ws + 49280);        // E*4 = 524288 -> 573568
  int* counts = (int*)(ws + 573568);         // M*4 = 262144 -> 835712
  double* aggd = (double*)(ws + 835712);     // M*8 = 524288 -> 1360000 (8-aligned)
  int* lists = (int*)(ws + 1360000);         // M*32*4 = 8388608 -> 9748608
  int* idxw = (int*)(ws + 9748608);          // B*K*4 = 65536 -> 9814144

  float* out_nodes = (float*)d_out;                       // B*K*2
  float* out_emd = (float*)d_out + (size_t)B * KTOP * 2;  // B*K*128
  float* out_hid = out_emd + (size_t)B * KTOP * 128;      // B*K*128

  hipMemsetAsync(counts, 0, MSEG * sizeof(int) + MSEG * sizeof(double), stream);
  k0_precompute<<<B, 384, 0, stream>>>(q_head, q_rel, q_time, W_q, b_q, W_a,
                                       b_a, W_att, b_att, vf, c2f);
  k1_att<<<E / 64, 256, 0, stream>>>(r_nb, t_nb, tm_nb, hidden, W_rule, b_rule,
                                     vf, c2f, tail_index, attw, aggd);
  kb_build<<<E / 256, 256, 0, stream>>>(tail_index, counts, lists);
  k6_topk<<<B * 8, 256, 0, stream>>>(aggd, tail_nodes, out_nodes, idxw);
  k7_out<<<(B * KTOP) / K7ROWS, 256, 0, stream>>>(tail_emd, r_nb, tm_nb,
                                                  hidden, q_head, attw, counts,
                                                  lists, W_out, b_out, idxw,
                                                  out_emd, out_hid);
}

// Round 2
// 431.726 us; speedup vs baseline: 1.0667x; 1.0287x over previous
//
#include <hip/hip_runtime.h>
#include <math.h>

// Problem constants
#define B 32
#define N 4096
#define D 128
#define KTOP 512
#define NPB 2048
#define MSEG (B * NPB)      // 65536
#define E (B * N)           // 131072
#define MAXC 32             // max edges per segment (Binomial(4096,1/2048), mean 2)
#define K7ROWS 16           // rows per k7 block

// ---------------------------------------------------------------------------
// K0: per-batch precompute (fp64) + cooperative zeroing of counts/aggd
// (absorbs the hipMemsetAsync dispatch; k0 finishes before k1 in stream order).
// 384 threads: 3 groups of 128 handle one input segment each, then one W_a row
// per thread in phase B.
// ---------------------------------------------------------------------------
__global__ __launch_bounds__(384) void k0_precompute(
    const float* __restrict__ qh, const float* __restrict__ qr,
    const float* __restrict__ qt, const float* __restrict__ Wq,
    const float* __restrict__ bq, const float* __restrict__ Wa,
    const float* __restrict__ ba, const float* __restrict__ Watt,
    const float* __restrict__ batt, float* __restrict__ vf,
    float* __restrict__ c2f, int* __restrict__ counts,
    double* __restrict__ aggd) {
  int b = blockIdx.x;
  int tid = threadIdx.x;
  // ---- cooperative zero of counts (256KB) + aggd (512KB), grid-stride ----
  {
    int t = b * 384 + tid;  // 0..12287
    float4 z = make_float4(0.f, 0.f, 0.f, 0.f);
    float4* cz = (float4*)counts;  // 16384 float4
    float4* az = (float4*)aggd;    // 32768 float4
    for (int i = t; i < 16384; i += 12288) cz[i] = z;
    for (int i = t; i < 32768; i += 12288) az[i] = z;
  }
  int d = tid & 127;
  int g = tid >> 7;  // 0..2, wave-uniform (384 = 6 waves)
  __shared__ double part[3][128];
  __shared__ double u[128];
  __shared__ double red[128];
  const float* xs = (g == 0 ? qh : (g == 1 ? qr : qt)) + b * 128;
  const float* Wg = Wq + g * 128 * 128;
  double a0 = 0, a1 = 0, a2 = 0, a3 = 0;
#pragma unroll 4
  for (int i = 0; i < 128; i += 4) {
    a0 += (double)xs[i] * (double)Wg[i * 128 + d];
    a1 += (double)xs[i + 1] * (double)Wg[(i + 1) * 128 + d];
    a2 += (double)xs[i + 2] * (double)Wg[(i + 2) * 128 + d];
    a3 += (double)xs[i + 3] * (double)Wg[(i + 3) * 128 + d];
  }
  part[g][d] = (a0 + a1) + (a2 + a3);
  __syncthreads();
  if (g == 0) {
    double acc = (double)bq[d] + part[0][d] + part[1][d] + part[2][d];
    double w1 = (double)Watt[d], w2 = (double)Watt[128 + d],
           w3 = (double)Watt[256 + d];
    double ud = acc * w1 - w2 + w3;
    u[d] = ud;
    red[d] = acc * (w2 + w3) + (double)ba[d] * ud;
  }
  __syncthreads();
  for (int s = 64; s > 0; s >>= 1) {
    if (tid < s) red[tid] += red[tid + s];
    __syncthreads();
  }
  if (tid == 0) c2f[b] = (float)(red[0] + (double)batt[0]);
  // phase B: one W_a row per thread (384 rows, 384 threads)
  {
    double v0 = 0, v1 = 0, v2 = 0, v3 = 0;
    const float* Wr = Wa + tid * 128;
#pragma unroll 4
    for (int dd = 0; dd < 128; dd += 4) {
      v0 += (double)Wr[dd] * u[dd];
      v1 += (double)Wr[dd + 1] * u[dd + 1];
      v2 += (double)Wr[dd + 2] * u[dd + 2];
      v3 += (double)Wr[dd + 3] * u[dd + 3];
    }
    vf[b * 384 + tid] = (float)((v0 + v1) + (v2 + v3));
  }
}

// ---------------------------------------------------------------------------
// K1: per-edge attention, fp32. 32 lanes per edge, float4 per lane.
// Depth-2 pipeline at <=64 VGPR (launch_bounds min 8 waves/EU) so full
// occupancy AND 8 outstanding loads/wave: 2x Round-0 in-flight bytes at the
// same occupancy -- the clean latency-vs-ceiling experiment.
// ALL vmem side effects (attw store, aggd fp64 atomic, and the fused kb_build
// counts/lists atomics) moved to a post-loop epilogue done by 8 lanes in
// parallel (butterfly reduce leaves the result in every lane, so lane i
// latches edge i) -- the hot loop contains loads + VALU only, so no
// compiler-inserted store waits can drain the prefetch queue.
// fp64 agg atomics: order-independent to ~1e-15, far below the rank-512
// boundary gap ~1e-3 -> ranking stable.
// ---------------------------------------------------------------------------
__global__ __launch_bounds__(256, 8) void k1_att(
    const float* __restrict__ r, const float* __restrict__ t,
    const float* __restrict__ tm, const float* __restrict__ hidden,
    const float* __restrict__ Wrule, const float* __restrict__ brule,
    const float* __restrict__ vf, const float* __restrict__ c2f,
    const int* __restrict__ tidx, float* __restrict__ attw,
    double* __restrict__ aggd, int* __restrict__ counts,
    int* __restrict__ lists) {
  int tid = threadIdx.x;
  int h = tid >> 5;       // half-wave id 0..7
  int l = tid & 31;       // lane within 32
  int base = blockIdx.x * 64;
  int b = base >> 12;     // batch (uniform over block)
  const float4* vb = (const float4*)(vf + b * 384);
  float4 v0 = vb[l];
  float4 v1 = vb[32 + l];
  float4 v2 = vb[64 + l];
  float4 wr = ((const float4*)Wrule)[l];
  float c2 = c2f[b];
  float br = brule[0];
  int myseg = 0;
  if (l < 8) myseg = tidx[base + l * 8 + h];
  float mya = 0.f;
  // 32-bit element offsets (same offset for all 4 arrays) -> saddr+voffset
  // addressing, minimal VGPR for the pipeline.
  unsigned lo = (unsigned)(l * 4);
  float4 ra[2], ta[2], ma[2], ha[2];
  {
    unsigned eo = ((unsigned)(base + h) << 7) + lo;
    ra[0] = *(const float4*)(r + eo);
    ta[0] = *(const float4*)(t + eo);
    ma[0] = *(const float4*)(tm + eo);
    ha[0] = *(const float4*)(hidden + eo);
  }
#pragma unroll
  for (int i = 0; i < 8; ++i) {
    const int cur = i & 1;
    if (i < 7) {  // prefetch next edge into the other slot
      const int nxt = cur ^ 1;
      unsigned eo = ((unsigned)(base + (i + 1) * 8 + h) << 7) + lo;
      ra[nxt] = *(const float4*)(r + eo);
      ta[nxt] = *(const float4*)(t + eo);
      ma[nxt] = *(const float4*)(tm + eo);
      ha[nxt] = *(const float4*)(hidden + eo);
    }
    float4 A = ra[cur], T = ta[cur], M = ma[cur], H = ha[cur];
    float p1 = A.x * v0.x + A.y * v0.y + A.z * v0.z + A.w * v0.w;
    p1 += T.x * v1.x + T.y * v1.y + T.z * v1.z + T.w * v1.w;
    p1 += M.x * v2.x + M.y * v2.y + M.z * v2.z + M.w * v2.w;
    float p2 = H.x * wr.x + H.y * wr.y + H.z * wr.z + H.w * wr.w;
#pragma unroll
    for (int off = 16; off > 0; off >>= 1) {
      p1 += __shfl_xor(p1, off);
      p2 += __shfl_xor(p2, off);
    }
    // every lane now holds the full reduction; lane i latches edge i
    if (l == i) {
      float a1 = 1.0f / (1.0f + expf(-(p1 + c2)));
      float a2 = 1.0f / (1.0f + expf(-(p2 + br)));
      mya = 0.5f * (a1 + a2);
    }
  }
  // ---- epilogue: 8 lanes in parallel do all bookkeeping (incl. fused kb) ----
  if (l < 8) {
    int e = base + l * 8 + h;
    attw[e] = mya;
    atomicAdd(&aggd[myseg], (double)mya);
    int pos = atomicAdd(&counts[myseg], 1);
    if (pos < MAXC) lists[myseg * MAXC + pos] = e;
  }
}

// ---------------------------------------------------------------------------
// K6: exact top-K by rank counting on fp64 agg. Block = (batch, 256 elems).
// rank(i) = #{j : v_j > v_i || (v_j == v_i && j < i)}  == lax.top_k position.
// ---------------------------------------------------------------------------
__global__ __launch_bounds__(256) void k6_topk(
    const double* __restrict__ aggd, const int* __restrict__ tail_nodes,
    float* __restrict__ out_nodes, int* __restrict__ idxw) {
  __shared__ double sv[2048];
  int b = blockIdx.x >> 3;
  int chunk = blockIdx.x & 7;
  int tid = threadIdx.x;
  for (int s = tid; s < 2048; s += 256) sv[s] = aggd[b * 2048 + s];
  __syncthreads();
  int i = chunk * 256 + tid;
  double vi = sv[i];
  int rank = 0;
#pragma unroll 8
  for (int j = 0; j < 2048; ++j) {
    double vj = sv[j];
    rank += (vj > vi) || (vj == vi && j < i);
  }
  if (rank < KTOP) {
    int gm = b * 2048 + i;
    int p = b * KTOP + rank;
    out_nodes[p * 2 + 0] = (float)tail_nodes[gm * 3 + 1];
    out_nodes[p * 2 + 1] = (float)tail_nodes[gm * 3 + 2];
    idxw[p] = gm;
  }
}

// ---------------------------------------------------------------------------
// K7: selected rows only. Phase 1: gather edges, segment-sum message/hidden
// into LDS es[16][128] (+out_hid). Dependent-load chain shortened by batching:
// all 8 idxw first, then counts + first-4-edge-ids (one int4) per row, then
// payloads -- 3 latency rounds instead of 2+2*cnt. Phase 2: out_emd =
// es @ W_out + b_out with W_out from L2 and 8 independent accs/thread.
// ---------------------------------------------------------------------------
__global__ __launch_bounds__(256) void k7_out(
    const float* __restrict__ tail_emd, const float* __restrict__ r,
    const float* __restrict__ tm, const float* __restrict__ hidden,
    const float* __restrict__ qh, const float* __restrict__ attw,
    const int* __restrict__ counts, const int* __restrict__ lists,
    const float* __restrict__ Wout, const float* __restrict__ bout,
    const int* __restrict__ idxw, float* __restrict__ out_emd,
    float* __restrict__ out_hid) {
  __shared__ float es[K7ROWS][128];
  int tid = threadIdx.x;
  int sub = tid >> 7, d = tid & 127;
  int base = blockIdx.x * K7ROWS;
  // ---- phase 1: gather + segment sums (sub-thread owns rows base+2*jj+sub) --
  int mrow[8], crow[8];
#pragma unroll
  for (int jj = 0; jj < 8; ++jj) mrow[jj] = idxw[base + jj * 2 + sub];
#pragma unroll
  for (int jj = 0; jj < 8; ++jj) crow[jj] = counts[mrow[jj]];
  int4 el[8];
#pragma unroll
  for (int jj = 0; jj < 8; ++jj)
    el[jj] = *(const int4*)(lists + (size_t)mrow[jj] * MAXC);
#pragma unroll
  for (int jj = 0; jj < 8; ++jj) {
    int m = mrow[jj];
    int bb = m >> 11;
    int cnt = crow[jj] > MAXC ? MAXC : crow[jj];
    float accT = tail_emd[(size_t)m * 128 + d];
    float accH = 0.f;
    float qhd = qh[bb * 128 + d];
    int e0 = el[jj].x, e1 = el[jj].y, e2 = el[jj].z, e3 = el[jj].w;
    if (cnt > 0) {
      float a = attw[e0];
      size_t eo = (size_t)e0 * 128 + d;
      accT += a * (qhd + r[eo] + tm[eo]);
      accH += hidden[eo];
    }
    if (cnt > 1) {
      float a = attw[e1];
      size_t eo = (size_t)e1 * 128 + d;
      accT += a * (qhd + r[eo] + tm[eo]);
      accH += hidden[eo];
    }
    if (cnt > 2) {
      float a = attw[e2];
      size_t eo = (size_t)e2 * 128 + d;
      accT += a * (qhd + r[eo] + tm[eo]);
      accH += hidden[eo];
    }
    if (cnt > 3) {
      float a = attw[e3];
      size_t eo = (size_t)e3 * 128 + d;
      accT += a * (qhd + r[eo] + tm[eo]);
      accH += hidden[eo];
    }
    for (int k = 4; k < cnt; ++k) {  // rare tail (P(cnt>4) small)
      int e = lists[(size_t)m * MAXC + k];
      float a = attw[e];
      size_t eo = (size_t)e * 128 + d;
      accT += a * (qhd + r[eo] + tm[eo]);
      accH += hidden[eo];
    }
    es[jj * 2 + sub][d] = accT;
    out_hid[(size_t)(base + jj * 2 + sub) * 128 + d] = accH;
  }
  __syncthreads();
  // ---- phase 2: GEMM es(16x128) @ Wout(128x128) ----
  int cg = tid & 31;   // columns cg*4 .. cg*4+3
  int rg = tid >> 5;   // row pair rg*2, rg*2+1
  float4 bo = *(const float4*)(bout + cg * 4);
  float acc0x = bo.x, acc0y = bo.y, acc0z = bo.z, acc0w = bo.w;
  float acc1x = bo.x, acc1y = bo.y, acc1z = bo.z, acc1w = bo.w;
#pragma unroll 4
  for (int i = 0; i < 128; ++i) {
    float4 w = *(const float4*)(Wout + i * 128 + cg * 4);
    float e0 = es[rg * 2 + 0][i];
    float e1 = es[rg * 2 + 1][i];
    acc0x += e0 * w.x; acc0y += e0 * w.y; acc0z += e0 * w.z; acc0w += e0 * w.w;
    acc1x += e1 * w.x; acc1y += e1 * w.y; acc1z += e1 * w.z; acc1w += e1 * w.w;
  }
  size_t r0 = (size_t)(base + rg * 2) * 128 + cg * 4;
  *(float4*)(out_emd + r0) = make_float4(acc0x, acc0y, acc0z, acc0w);
  *(float4*)(out_emd + r0 + 128) = make_float4(acc1x, acc1y, acc1z, acc1w);
}

// ---------------------------------------------------------------------------
extern "C" void kernel_launch(void* const* d_in, const int* in_sizes, int n_in,
                              void* d_out, int out_size, void* d_ws,
                              size_t ws_size, hipStream_t stream) {
  const float* q_head = (const float*)d_in[0];
  const float* q_rel = (const float*)d_in[1];
  const float* q_time = (const float*)d_in[2];
  const float* r_nb = (const float*)d_in[3];
  const float* t_nb = (const float*)d_in[4];
  const float* tm_nb = (const float*)d_in[5];
  const float* hidden = (const float*)d_in[6];
  const float* tail_emd = (const float*)d_in[7];
  const int* tail_index = (const int*)d_in[8];
  const int* tail_nodes = (const int*)d_in[9];
  const float* W_q = (const float*)d_in[10];
  const float* b_q = (const float*)d_in[11];
  const float* W_a = (const float*)d_in[12];
  const float* b_a = (const float*)d_in[13];
  const float* W_att = (const float*)d_in[14];
  const float* b_att = (const float*)d_in[15];
  const float* W_rule = (const float*)d_in[16];
  const float* b_rule = (const float*)d_in[17];
  const float* W_out = (const float*)d_in[18];
  const float* b_out = (const float*)d_in[19];

  char* ws = (char*)d_ws;
  float* vf = (float*)(ws + 0);              // 32*384*4 = 49152
  float* c2f = (float*)(ws + 49152);         // 128 -> pad to 49280
  float* attw = (float*)(ws + 49280);        // E*4 = 524288 -> 573568
  int* counts = (int*)(ws + 573568);         // M*4 = 262144 -> 835712
  double* aggd = (double*)(ws + 835712);     // M*8 = 524288 -> 1360000
  int* lists = (int*)(ws + 1360000);         // M*32*4 = 8388608 -> 9748608
  int* idxw = (int*)(ws + 9748608);          // B*K*4 = 65536 -> 9814144

  float* out_nodes = (float*)d_out;                       // B*K*2
  float* out_emd = (float*)d_out + (size_t)B * KTOP * 2;  // B*K*128
  float* out_hid = out_emd + (size_t)B * KTOP * 128;      // B*K*128

  // 4 dispatches total: memset folded into k0, kb_build fused into k1.
  k0_precompute<<<B, 384, 0, stream>>>(q_head, q_rel, q_time, W_q, b_q, W_a,
                                       b_a, W_att, b_att, vf, c2f, counts,
                                       aggd);
  k1_att<<<E / 64, 256, 0, stream>>>(r_nb, t_nb, tm_nb, hidden, W_rule, b_rule,
                                     vf, c2f, tail_index, attw, aggd, counts,
                                     lists);
  k6_topk<<<B * 8, 256, 0, stream>>>(aggd, tail_nodes, out_nodes, idxw);
  k7_out<<<(B * KTOP) / K7ROWS, 256, 0, stream>>>(tail_emd, r_nb, tm_nb,
                                                  hidden, q_head, attw, counts,
                                                  lists, W_out, b_out, idxw,
                                                  out_emd, out_hid);
}

// Round 3
// 424.899 us; speedup vs baseline: 1.0838x; 1.0161x over previous
//
#include <hip/hip_runtime.h>
#include <math.h>

// Problem constants
#define B 32
#define N 4096
#define D 128
#define KTOP 512
#define NPB 2048
#define MSEG (B * NPB)      // 65536
#define E (B * N)           // 131072
#define MAXC 32             // max edges per segment (Binomial(4096,1/2048), mean 2)
#define K7ROWS 16           // rows per k7 block

// ---------------------------------------------------------------------------
// K0: per-batch precompute (fp64) + cooperative zeroing of counts/aggd.
// ---------------------------------------------------------------------------
__global__ __launch_bounds__(384) void k0_precompute(
    const float* __restrict__ qh, const float* __restrict__ qr,
    const float* __restrict__ qt, const float* __restrict__ Wq,
    const float* __restrict__ bq, const float* __restrict__ Wa,
    const float* __restrict__ ba, const float* __restrict__ Watt,
    const float* __restrict__ batt, float* __restrict__ vf,
    float* __restrict__ c2f, int* __restrict__ counts,
    double* __restrict__ aggd) {
  int b = blockIdx.x;
  int tid = threadIdx.x;
  // ---- cooperative zero of counts (256KB) + aggd (512KB), grid-stride ----
  {
    int t = b * 384 + tid;  // 0..12287
    float4 z = make_float4(0.f, 0.f, 0.f, 0.f);
    float4* cz = (float4*)counts;  // 16384 float4
    float4* az = (float4*)aggd;    // 32768 float4
    for (int i = t; i < 16384; i += 12288) cz[i] = z;
    for (int i = t; i < 32768; i += 12288) az[i] = z;
  }
  int d = tid & 127;
  int g = tid >> 7;  // 0..2, wave-uniform (384 = 6 waves)
  __shared__ double part[3][128];
  __shared__ double u[128];
  __shared__ double red[128];
  const float* xs = (g == 0 ? qh : (g == 1 ? qr : qt)) + b * 128;
  const float* Wg = Wq + g * 128 * 128;
  double a0 = 0, a1 = 0, a2 = 0, a3 = 0;
#pragma unroll 4
  for (int i = 0; i < 128; i += 4) {
    a0 += (double)xs[i] * (double)Wg[i * 128 + d];
    a1 += (double)xs[i + 1] * (double)Wg[(i + 1) * 128 + d];
    a2 += (double)xs[i + 2] * (double)Wg[(i + 2) * 128 + d];
    a3 += (double)xs[i + 3] * (double)Wg[(i + 3) * 128 + d];
  }
  part[g][d] = (a0 + a1) + (a2 + a3);
  __syncthreads();
  if (g == 0) {
    double acc = (double)bq[d] + part[0][d] + part[1][d] + part[2][d];
    double w1 = (double)Watt[d], w2 = (double)Watt[128 + d],
           w3 = (double)Watt[256 + d];
    double ud = acc * w1 - w2 + w3;
    u[d] = ud;
    red[d] = acc * (w2 + w3) + (double)ba[d] * ud;
  }
  __syncthreads();
  for (int s = 64; s > 0; s >>= 1) {
    if (tid < s) red[tid] += red[tid + s];
    __syncthreads();
  }
  if (tid == 0) c2f[b] = (float)(red[0] + (double)batt[0]);
  // phase B: one W_a row per thread (384 rows, 384 threads)
  {
    double v0 = 0, v1 = 0, v2 = 0, v3 = 0;
    const float* Wr = Wa + tid * 128;
#pragma unroll 4
    for (int dd = 0; dd < 128; dd += 4) {
      v0 += (double)Wr[dd] * u[dd];
      v1 += (double)Wr[dd + 1] * u[dd + 1];
      v2 += (double)Wr[dd + 2] * u[dd + 2];
      v3 += (double)Wr[dd + 3] * u[dd + 3];
    }
    vf[b * 384 + tid] = (float)((v0 + v1) + (v2 + v3));
  }
}

// ---------------------------------------------------------------------------
// K1: per-edge attention, fp32. 32 lanes per edge, float4 per lane.
// Grid 1024 blocks x 2 passes of 64 edges: amortizes the vf/Wrule preamble 2x
// and halves block churn (k1 is scheduling-invariant per R0-R2, so lower
// residency is safe; R1 ran fastest at 26% occupancy).
// Fused kb_build writes u16 local edge ids (12 bits suffice given the
// segment's batch): one 64B line per segment instead of two -> less
// write-allocate RMW traffic (R2's +14MB WRITE_SIZE regression).
// fp64 agg atomics: order-independent to ~1e-15, far below the rank-512
// boundary gap ~1e-3 -> ranking stable.
// ---------------------------------------------------------------------------
__global__ __launch_bounds__(256, 8) void k1_att(
    const float* __restrict__ r, const float* __restrict__ t,
    const float* __restrict__ tm, const float* __restrict__ hidden,
    const float* __restrict__ Wrule, const float* __restrict__ brule,
    const float* __restrict__ vf, const float* __restrict__ c2f,
    const int* __restrict__ tidx, float* __restrict__ attw,
    double* __restrict__ aggd, int* __restrict__ counts,
    unsigned short* __restrict__ lists) {
  int tid = threadIdx.x;
  int h = tid >> 5;       // half-wave id 0..7
  int l = tid & 31;       // lane within 32
  int blk = blockIdx.x;   // 1024 blocks, 32 per batch
  int b = blk >> 5;       // batch (uniform over block)
  const float4* vb = (const float4*)(vf + b * 384);
  float4 v0 = vb[l];
  float4 v1 = vb[32 + l];
  float4 v2 = vb[64 + l];
  float4 wr = ((const float4*)Wrule)[l];
  float c2 = c2f[b];
  float br = brule[0];
  unsigned lo = (unsigned)(l * 4);
  for (int pass = 0; pass < 2; ++pass) {
    int base = blk * 128 + pass * 64;
    int myseg = 0;
    if (l < 8) myseg = tidx[base + l * 8 + h];
    float mya = 0.f;
    float4 ra[2], ta[2], ma[2], ha[2];
    {
      unsigned eo = ((unsigned)(base + h) << 7) + lo;
      ra[0] = *(const float4*)(r + eo);
      ta[0] = *(const float4*)(t + eo);
      ma[0] = *(const float4*)(tm + eo);
      ha[0] = *(const float4*)(hidden + eo);
    }
#pragma unroll
    for (int i = 0; i < 8; ++i) {
      const int cur = i & 1;
      if (i < 7) {  // prefetch next edge into the other slot
        const int nxt = cur ^ 1;
        unsigned eo = ((unsigned)(base + (i + 1) * 8 + h) << 7) + lo;
        ra[nxt] = *(const float4*)(r + eo);
        ta[nxt] = *(const float4*)(t + eo);
        ma[nxt] = *(const float4*)(tm + eo);
        ha[nxt] = *(const float4*)(hidden + eo);
      }
      float4 A = ra[cur], T = ta[cur], M = ma[cur], H = ha[cur];
      float p1 = A.x * v0.x + A.y * v0.y + A.z * v0.z + A.w * v0.w;
      p1 += T.x * v1.x + T.y * v1.y + T.z * v1.z + T.w * v1.w;
      p1 += M.x * v2.x + M.y * v2.y + M.z * v2.z + M.w * v2.w;
      float p2 = H.x * wr.x + H.y * wr.y + H.z * wr.z + H.w * wr.w;
#pragma unroll
      for (int off = 16; off > 0; off >>= 1) {
        p1 += __shfl_xor(p1, off);
        p2 += __shfl_xor(p2, off);
      }
      // every lane now holds the full reduction; lane i latches edge i
      if (l == i) {
        float a1 = 1.0f / (1.0f + expf(-(p1 + c2)));
        float a2 = 1.0f / (1.0f + expf(-(p2 + br)));
        mya = 0.5f * (a1 + a2);
      }
    }
    // ---- epilogue: 8 lanes in parallel do all bookkeeping (fused kb) ----
    if (l < 8) {
      int e = base + l * 8 + h;
      attw[e] = mya;
      atomicAdd(&aggd[myseg], (double)mya);
      int pos = atomicAdd(&counts[myseg], 1);
      if (pos < MAXC)
        lists[(unsigned)myseg * MAXC + pos] = (unsigned short)(e & 4095);
    }
  }
}

// ---------------------------------------------------------------------------
// K6: exact top-K by rank counting on fp64 agg. Block = (batch, 256 elems).
// rank(i) = #{j : v_j > v_i || (v_j == v_i && j < i)}  == lax.top_k position.
// ---------------------------------------------------------------------------
__global__ __launch_bounds__(256) void k6_topk(
    const double* __restrict__ aggd, const int* __restrict__ tail_nodes,
    float* __restrict__ out_nodes, int* __restrict__ idxw) {
  __shared__ double sv[2048];
  int b = blockIdx.x >> 3;
  int chunk = blockIdx.x & 7;
  int tid = threadIdx.x;
  for (int s = tid; s < 2048; s += 256) sv[s] = aggd[b * 2048 + s];
  __syncthreads();
  int i = chunk * 256 + tid;
  double vi = sv[i];
  int rank = 0;
#pragma unroll 8
  for (int j = 0; j < 2048; ++j) {
    double vj = sv[j];
    rank += (vj > vi) || (vj == vi && j < i);
  }
  if (rank < KTOP) {
    int gm = b * 2048 + i;
    int p = b * KTOP + rank;
    out_nodes[p * 2 + 0] = (float)tail_nodes[gm * 3 + 1];
    out_nodes[p * 2 + 1] = (float)tail_nodes[gm * 3 + 2];
    idxw[p] = gm;
  }
}

// ---------------------------------------------------------------------------
// K7: selected rows only. Phase 1: gather edges, segment-sum message/hidden
// into LDS es[16][128] (+out_hid). First 4 edges per row are PREDICATED
// (unconditional loads from clamped-safe decoded addresses, contribution
// masked) so the compiler can put all 8 rows x 4 edges x 4 streams in flight
// -- no branch serialization of the gather. u16 list decode:
// e = batch*4096 | local. Rare tail (cnt>4, ~40% of selected rows, mean ~0.6
// extra edges) stays branchy. Phase 2: out_emd = es @ W_out + b_out.
// ---------------------------------------------------------------------------
__global__ __launch_bounds__(256) void k7_out(
    const float* __restrict__ tail_emd, const float* __restrict__ r,
    const float* __restrict__ tm, const float* __restrict__ hidden,
    const float* __restrict__ qh, const float* __restrict__ attw,
    const int* __restrict__ counts, const unsigned short* __restrict__ lists,
    const float* __restrict__ Wout, const float* __restrict__ bout,
    const int* __restrict__ idxw, float* __restrict__ out_emd,
    float* __restrict__ out_hid) {
  __shared__ float es[K7ROWS][128];
  int tid = threadIdx.x;
  int sub = tid >> 7, d = tid & 127;
  int base = blockIdx.x * K7ROWS;
  // ---- phase 1: batched index rounds, then predicated payload gather ----
  int mrow[8], crow[8];
#pragma unroll
  for (int jj = 0; jj < 8; ++jj) mrow[jj] = idxw[base + jj * 2 + sub];
#pragma unroll
  for (int jj = 0; jj < 8; ++jj) crow[jj] = counts[mrow[jj]];
  uint2 el[8];
#pragma unroll
  for (int jj = 0; jj < 8; ++jj)
    el[jj] = *(const uint2*)(lists + (size_t)mrow[jj] * MAXC);
#pragma unroll
  for (int jj = 0; jj < 8; ++jj) {
    int m = mrow[jj];
    int bb = m >> 11;
    unsigned ebase = (unsigned)bb << 12;
    int cnt = crow[jj] > MAXC ? MAXC : crow[jj];
    float accT = tail_emd[(size_t)m * 128 + d];
    float accH = 0.f;
    float qhd = qh[bb * 128 + d];
    // decode first 4 edge ids; garbage (cnt==0) still lands in-batch -> safe
    unsigned e0 = ebase | (el[jj].x & 0xFFFFu);
    unsigned e1 = ebase | (el[jj].x >> 16);
    unsigned e2 = ebase | (el[jj].y & 0xFFFFu);
    unsigned e3 = ebase | (el[jj].y >> 16);
    float m0 = cnt > 0 ? 1.f : 0.f;
    float m1 = cnt > 1 ? 1.f : 0.f;
    float m2 = cnt > 2 ? 1.f : 0.f;
    float m3 = cnt > 3 ? 1.f : 0.f;
    // unconditional loads (predicated accumulate) -> full MLP
    float a0 = attw[e0], a1 = attw[e1], a2 = attw[e2], a3 = attw[e3];
    unsigned o0 = (e0 << 7) + d, o1 = (e1 << 7) + d;
    unsigned o2 = (e2 << 7) + d, o3 = (e3 << 7) + d;
    float r0 = r[o0], r1 = r[o1], r2 = r[o2], r3 = r[o3];
    float t0 = tm[o0], t1 = tm[o1], t2 = tm[o2], t3 = tm[o3];
    float h0 = hidden[o0], h1 = hidden[o1], h2 = hidden[o2], h3 = hidden[o3];
    accT += m0 * a0 * (qhd + r0 + t0);
    accT += m1 * a1 * (qhd + r1 + t1);
    accT += m2 * a2 * (qhd + r2 + t2);
    accT += m3 * a3 * (qhd + r3 + t3);
    accH += m0 * h0 + m1 * h1 + m2 * h2 + m3 * h3;
    for (int k = 4; k < cnt; ++k) {  // tail: selected rows mean ~0.6 extra
      unsigned e = ebase | lists[(size_t)m * MAXC + k];
      float a = attw[e];
      unsigned eo = (e << 7) + d;
      accT += a * (qhd + r[eo] + tm[eo]);
      accH += hidden[eo];
    }
    es[jj * 2 + sub][d] = accT;
    out_hid[(size_t)(base + jj * 2 + sub) * 128 + d] = accH;
  }
  __syncthreads();
  // ---- phase 2: GEMM es(16x128) @ Wout(128x128) ----
  int cg = tid & 31;   // columns cg*4 .. cg*4+3
  int rg = tid >> 5;   // row pair rg*2, rg*2+1
  float4 bo = *(const float4*)(bout + cg * 4);
  float acc0x = bo.x, acc0y = bo.y, acc0z = bo.z, acc0w = bo.w;
  float acc1x = bo.x, acc1y = bo.y, acc1z = bo.z, acc1w = bo.w;
#pragma unroll 4
  for (int i = 0; i < 128; ++i) {
    float4 w = *(const float4*)(Wout + i * 128 + cg * 4);
    float e0 = es[rg * 2 + 0][i];
    float e1 = es[rg * 2 + 1][i];
    acc0x += e0 * w.x; acc0y += e0 * w.y; acc0z += e0 * w.z; acc0w += e0 * w.w;
    acc1x += e1 * w.x; acc1y += e1 * w.y; acc1z += e1 * w.z; acc1w += e1 * w.w;
  }
  size_t r0o = (size_t)(base + rg * 2) * 128 + cg * 4;
  *(float4*)(out_emd + r0o) = make_float4(acc0x, acc0y, acc0z, acc0w);
  *(float4*)(out_emd + r0o + 128) = make_float4(acc1x, acc1y, acc1z, acc1w);
}

// ---------------------------------------------------------------------------
extern "C" void kernel_launch(void* const* d_in, const int* in_sizes, int n_in,
                              void* d_out, int out_size, void* d_ws,
                              size_t ws_size, hipStream_t stream) {
  const float* q_head = (const float*)d_in[0];
  const float* q_rel = (const float*)d_in[1];
  const float* q_time = (const float*)d_in[2];
  const float* r_nb = (const float*)d_in[3];
  const float* t_nb = (const float*)d_in[4];
  const float* tm_nb = (const float*)d_in[5];
  const float* hidden = (const float*)d_in[6];
  const float* tail_emd = (const float*)d_in[7];
  const int* tail_index = (const int*)d_in[8];
  const int* tail_nodes = (const int*)d_in[9];
  const float* W_q = (const float*)d_in[10];
  const float* b_q = (const float*)d_in[11];
  const float* W_a = (const float*)d_in[12];
  const float* b_a = (const float*)d_in[13];
  const float* W_att = (const float*)d_in[14];
  const float* b_att = (const float*)d_in[15];
  const float* W_rule = (const float*)d_in[16];
  const float* b_rule = (const float*)d_in[17];
  const float* W_out = (const float*)d_in[18];
  const float* b_out = (const float*)d_in[19];

  char* ws = (char*)d_ws;
  float* vf = (float*)(ws + 0);               // 32*384*4 = 49152
  float* c2f = (float*)(ws + 49152);          // 128 -> pad to 49280
  float* attw = (float*)(ws + 49280);         // E*4 = 524288 -> 573568
  int* counts = (int*)(ws + 573568);          // M*4 = 262144 -> 835712
  double* aggd = (double*)(ws + 835712);      // M*8 = 524288 -> 1360000
  unsigned short* lists = (unsigned short*)(ws + 1360000);  // M*32*2 = 4194304 -> 5554304
  int* idxw = (int*)(ws + 5554304);           // B*K*4 = 65536 -> 5619840

  float* out_nodes = (float*)d_out;                       // B*K*2
  float* out_emd = (float*)d_out + (size_t)B * KTOP * 2;  // B*K*128
  float* out_hid = out_emd + (size_t)B * KTOP * 128;      // B*K*128

  // 4 dispatches total: memset folded into k0, kb_build fused into k1.
  k0_precompute<<<B, 384, 0, stream>>>(q_head, q_rel, q_time, W_q, b_q, W_a,
                                       b_a, W_att, b_att, vf, c2f, counts,
                                       aggd);
  k1_att<<<E / 128, 256, 0, stream>>>(r_nb, t_nb, tm_nb, hidden, W_rule,
                                      b_rule, vf, c2f, tail_index, attw, aggd,
                                      counts, lists);
  k6_topk<<<B * 8, 256, 0, stream>>>(aggd, tail_nodes, out_nodes, idxw);
  k7_out<<<(B * KTOP) / K7ROWS, 256, 0, stream>>>(tail_emd, r_nb, tm_nb,
                                                  hidden, q_head, attw, counts,
                                                  lists, W_out, b_out, idxw,
                                                  out_emd, out_hid);
}